// Round 12
// baseline (668.610 us; speedup 1.0000x reference)
//
#include <hip/hip_runtime.h>
#include <hip/hip_bf16.h>
#include <cstddef>

#define N_NODES 100000
#define N_EDGES 600000
#define DD 128
#define LL 3
#define CC 40
#define BN_EPS 1e-5f

typedef __attribute__((ext_vector_type(8))) short bfrag;   // 8 bf16 = 4 VGPRs
typedef __attribute__((ext_vector_type(4))) float f32x4;

// dtype-adaptive load/store: f32!=0 -> buffer holds float32, else bfloat16.
__device__ __forceinline__ float ldf(const void* p, long i, int f32) {
    return f32 ? ((const float*)p)[i] : __bfloat162float(((const __hip_bfloat16*)p)[i]);
}
__device__ __forceinline__ void stf(void* p, long i, float v, int f32) {
    if (f32) ((float*)p)[i] = v;
    else     ((__hip_bfloat16*)p)[i] = __float2bfloat16(v);
}

// float -> bf16 bits with round-to-nearest-even (finite inputs)
__device__ __forceinline__ unsigned short f2bf(float f) {
    unsigned u = __float_as_uint(f);
    unsigned r = (u + 0x7fffu + ((u >> 16) & 1u)) >> 16;
    return (unsigned short)r;
}
__device__ __forceinline__ float bf2f(unsigned short h) {
    return __uint_as_float(((unsigned)h) << 16);
}

// async global->LDS, 16B per lane (dest = wave-uniform base + lane*16)
__device__ __forceinline__ void gload_lds16(const unsigned short* g, unsigned short* l) {
    __builtin_amdgcn_global_load_lds((const __attribute__((address_space(1))) unsigned int*)g,
                                     (__attribute__((address_space(3))) unsigned int*)l, 16, 0, 0);
}

// ---------------- dtype detection (fp32 data read as bf16 -> garbage values) ----------------
__global__ __launch_bounds__(256) void k_detect(const void* __restrict__ x, int* __restrict__ dflag) {
    __shared__ int s[256];
    int t = threadIdx.x;
    const __hip_bfloat16* xb = (const __hip_bfloat16*)x;
    int bad = 0;
    for (int i = t; i < 4096; i += 256) {
        float v = __bfloat162float(xb[i]);
        float a = fabsf(v);
        if (!(a < 1e6f)) bad++;
        else if (v != 0.f && a < 1e-30f) bad++;
    }
    s[t] = bad; __syncthreads();
    for (int off = 128; off > 0; off >>= 1) {
        if (t < off) s[t] += s[t + off];
        __syncthreads();
    }
    if (t == 0) *dflag = (s[0] > 64) ? 1 : 0;
}

// ---------------- weight packing: fp32 W[128x128] -> bf16 hi/mid/lo planes, MFMA fragment order ----
// B-frag layout (16x16x32): lane holds W[k = ks*32 + (lane>>4)*8 + j][n*16 + (lane&15)].
// Packed (bf16 units, per matrix 49152): frag (n,ks,plane) at ((n*4+ks)*3+plane)*512 + lane*8 + j.
// n-major => one 64-col half (n 0..3 or 4..7) is a contiguous 24576-short (48 KB) range.
__global__ __launch_bounds__(256) void k_packw(const void* __restrict__ Ws, const void* __restrict__ Wh1,
                                               unsigned short* __restrict__ Wp,
                                               const int* __restrict__ dflag) {
    int f = *dflag;
    int u = blockIdx.x * 256 + threadIdx.x;      // 0 .. 65535 (4 matrices x 16384)
    int mat = u >> 14;
    int r = u & 16383;
    int k = r >> 7, c = r & 127;
    float wv = (mat < 3) ? ldf(Ws, (long)mat * 16384 + r, f) : ldf(Wh1, r, f);
    unsigned short hi = f2bf(wv);
    float r1 = wv - bf2f(hi);        // exact
    unsigned short mid = f2bf(r1);
    float r2 = r1 - bf2f(mid);       // exact
    unsigned short lo = f2bf(r2);
    int n = c >> 4, ks = k >> 5, j = k & 7;
    int lanep = (c & 15) | (((k >> 3) & 3) << 4);
    long base = (long)mat * 49152 + (long)((n * 4 + ks) * 3) * 512 + lanep * 8 + j;
    Wp[base] = hi;
    Wp[base + 512] = mid;
    Wp[base + 1024] = lo;
}

// ---------------- graph preprocessing ----------------

__global__ __launch_bounds__(256) void k_init(int* cnt, int* fpos, int* rowptr, float* stats) {
    int i = blockIdx.x * 256 + threadIdx.x;
    if (i < N_NODES) { cnt[i] = 0; fpos[i] = 0; }
    if (i < 6 * DD) stats[i] = 0.f;       // 3 layers x (sum[128], sumsq[128])
    if (i == 0) rowptr[N_NODES] = N_EDGES;
}

__global__ __launch_bounds__(256) void k_count(const int* __restrict__ ei, int* __restrict__ cnt) {
    int e = blockIdx.x * 256 + threadIdx.x;
    if (e < N_EDGES) atomicAdd(&cnt[ei[N_EDGES + e]], 1);  // dst row
}

__global__ __launch_bounds__(256) void k_scan1(const int* __restrict__ cnt, int* __restrict__ rowptr,
                                               int* __restrict__ bsum, float* __restrict__ dinv) {
    __shared__ int s[256];
    int t = threadIdx.x;
    int i = blockIdx.x * 256 + t;
    int v = (i < N_NODES) ? cnt[i] : 0;
    if (i < N_NODES) dinv[i] = 1.f / sqrtf((float)(1 + v));  // deg >= 1 (self-loop)
    s[t] = v; __syncthreads();
    for (int off = 1; off < 256; off <<= 1) {
        int x = (t >= off) ? s[t - off] : 0;
        __syncthreads();
        s[t] += x; __syncthreads();
    }
    if (i < N_NODES) rowptr[i] = s[t] - v;
    if (t == 255) bsum[blockIdx.x] = s[255];
}

__global__ __launch_bounds__(512) void k_scan2(int* bsum, int nb) {
    __shared__ int s[512];
    int t = threadIdx.x;
    int v = (t < nb) ? bsum[t] : 0;
    s[t] = v; __syncthreads();
    for (int off = 1; off < 512; off <<= 1) {
        int x = (t >= off) ? s[t - off] : 0;
        __syncthreads();
        s[t] += x; __syncthreads();
    }
    if (t < nb) bsum[t] = s[t] - v;
}

__global__ __launch_bounds__(256) void k_scan3(int* rowptr, const int* __restrict__ bsum) {
    int i = blockIdx.x * 256 + threadIdx.x;
    if (i < N_NODES) rowptr[i] += bsum[blockIdx.x];
}

// fill CSR adjacency as (src, dinv[src]) pairs: one coalesced int2 stream for k_agg
__global__ __launch_bounds__(256) void k_fill(const int* __restrict__ ei, int* __restrict__ fpos,
                                              const int* __restrict__ rowptr, int2* __restrict__ adjw,
                                              const float* __restrict__ dinv) {
    int e = blockIdx.x * 256 + threadIdx.x;
    if (e < N_EDGES) {
        int s = ei[e];
        int d = ei[N_EDGES + e];
        int p = atomicAdd(&fpos[d], 1);
        adjw[rowptr[d] + p] = make_int2(s, __float_as_int(dinv[s]));
    }
}

// ---- gather one feature row as float4 per 32-lane half: lane q owns elems 4q..4q+3 ----
__device__ __forceinline__ float4 load_row4(const void* __restrict__ src, long row, int q, int f) {
    if (f) {
        return ((const float4*)src)[row * 32 + q];
    } else {
        uint2 u = ((const uint2*)src)[row * 32 + q];
        float4 v;
        v.x = __uint_as_float(u.x << 16);
        v.y = __uint_as_float(u.x & 0xffff0000u);
        v.z = __uint_as_float(u.y << 16);
        v.w = __uint_as_float(u.y & 0xffff0000u);
        return v;
    }
}

__device__ __forceinline__ float4 bn4(float4 v, float4 sc, float4 sh, float al) {
    float y;
    y = fmaf(v.x, sc.x, sh.x); v.x = (y > 0.f) ? y : al * y;
    y = fmaf(v.y, sc.y, sh.y); v.y = (y > 0.f) ? y : al * y;
    y = fmaf(v.z, sc.z, sh.z); v.z = (y > 0.f) ? y : al * y;
    y = fmaf(v.w, sc.w, sh.w); v.w = (y > 0.f) ? y : al * y;
    return v;
}

// ---- CSR aggregation (agg-first): out_i = dinv_i*(dinv_i*act_i + sum_j dinv_j*act_j) ----
// act = identity for layer 0 (stats==null), else BN_{bnl}+PReLU with per-channel scale/shift
// computed ONCE PER BLOCK into LDS (threads 0-127).
// ONE ROW PER 32-LANE HALF (8 rows/block). At its measured pattern floor (~68 us,
// ~3.8 TB/s L2-miss traffic) across three MLP structures — do not touch.

__global__ __launch_bounds__(256) void k_agg(const void* __restrict__ src,
                                             const int* __restrict__ rowptr,
                                             const int2* __restrict__ adjw,
                                             const float* __restrict__ dinv,
                                             const float* __restrict__ stats,
                                             const void* __restrict__ gam,
                                             const void* __restrict__ bet,
                                             const void* __restrict__ pa,
                                             int bnl,
                                             float* __restrict__ outp,
                                             const int* __restrict__ dflag) {
    __shared__ float s_bn[260];            // sc[128], sh[128], alpha
    int f = *dflag;
    int tid = threadIdx.x;
    bool useBN = (stats != nullptr);
    if (useBN) {                           // per-block BN prep (uniform branch)
        if (tid < 128) {
            const float invn = 1.f / (float)N_NODES;
            float mean = stats[tid] * invn;
            float varv = stats[128 + tid] * invn - mean * mean;
            float s = ldf(gam, (long)bnl * DD + tid, f) / sqrtf(varv + BN_EPS);
            s_bn[tid] = s;
            s_bn[128 + tid] = ldf(bet, (long)bnl * DD + tid, f) - mean * s;
        }
        if (tid == 0) s_bn[256] = ldf(pa, bnl, f);
        __syncthreads();
    }

    int lane = tid & 63;
    int h = lane >> 5;                 // half: 0 or 1
    int q = lane & 31;                 // owns elems 4q..4q+3 of its half's row
    int i = blockIdx.x * 8 + ((tid >> 6) << 1) + h;   // one row per half-wave
    if (i >= N_NODES) return;

    float4 sc = make_float4(1.f, 1.f, 1.f, 1.f);
    float4 sh = make_float4(0.f, 0.f, 0.f, 0.f);
    float al = 0.f;
    if (useBN) {
        sc = ((const float4*)s_bn)[q];
        sh = ((const float4*)(s_bn + 128))[q];
        al = s_bn[256];
    }

    float di = dinv[i];
    int e0 = rowptr[i], e1 = rowptr[i + 1];

    // self term
    float4 v = load_row4(src, i, q, f);
    if (useBN) v = bn4(v, sc, sh, al);
    float a0 = di * v.x, a1 = di * v.y, a2 = di * v.z, a3 = di * v.w;

    for (int base = e0; base < e1; base += 32) {
        int m = e1 - base; if (m > 32) m = 32;
        int2 aw = (q < m) ? adjw[base + q] : make_int2(0, 0);   // coalesced 8B per half
        int ajl = aw.x;
        float wl = __int_as_float(aw.y);                         // zero beyond m
        for (int t = 0; t < m; t += 2) {
            int j0 = __shfl(ajl, t, 32);                         // width-32: half-local
            int j1 = __shfl(ajl, t + 1, 32);                     // wl beyond m is 0
            float w0 = __shfl(wl, t, 32);
            float w1 = __shfl(wl, t + 1, 32);
            float4 v0 = load_row4(src, j0, q, f);                // 2 gathers in flight/half
            float4 v1 = load_row4(src, j1, q, f);                // (4 per wave)
            if (useBN) {
                v0 = bn4(v0, sc, sh, al);
                v1 = bn4(v1, sc, sh, al);
            }
            a0 += w0 * v0.x + w1 * v1.x;
            a1 += w0 * v0.y + w1 * v1.y;
            a2 += w0 * v0.z + w1 * v1.z;
            a3 += w0 * v0.w + w1 * v1.w;
        }
    }

    float4 r = make_float4(di * a0, di * a1, di * a2, di * a3);
    ((float4*)outp)[(size_t)i * 32 + q] = r;
}

// ---- MFMA GEMM: C[N x 128] = act(A)[N x 128] * W[128 x 128] + bias (opt relu) ----
// R7-structure transplant (measured 78 us vs 91 for the 128-row form):
// 64-row blocks (grid 1563), 16 rows/wave, n-outermost dual accumulators (8 VGPR),
// W staged in two 48 KB halves via global_load_lds; half-0 issued BEFORE A-load/convert.
// Stats accumulated in regs, reduce overlaid into Wl after final read -> LDS = 48 KB exact.
// statsA: BN_{bnl}+PReLU on A inline (head GEMM); embp: write act(A) (= embeddings).

__global__ __launch_bounds__(256, 3) void k_gemm2(const float* __restrict__ A,
                                                  const unsigned short* __restrict__ Wp,
                                                  const void* __restrict__ bias, long boff,
                                                  const float* __restrict__ statsA,
                                                  const void* __restrict__ gam,
                                                  const void* __restrict__ bet,
                                                  const void* __restrict__ pa, int bnl,
                                                  float* __restrict__ stats,
                                                  float* __restrict__ Cout,
                                                  void* __restrict__ embp, int relu,
                                                  const int* __restrict__ dflag) {
    __shared__ unsigned short Wl[24576];      // 48 KB exactly; overlaid for stats reduce
    int f = *dflag;
    int tid = threadIdx.x;
    int lane = tid & 63;
    int w = tid >> 6;
    int lr = lane & 15;               // A-row-in-subtile / C-col-in-tile
    int lg = lane >> 4;               // 0..3 (k-group)
    int rowbase = blockIdx.x * 64 + w * 16;
    int arow = rowbase + lr;          // the A row this lane loads
    bool rowok = arow < N_NODES;

    // ---- stage half 0 async (12 x 1KB chunks per wave)
    #pragma unroll
    for (int u = 0; u < 12; ++u) {
        int chunk = w * 12 + u;
        gload_lds16(Wp + chunk * 512 + lane * 8, &Wl[chunk * 512]);
    }

    float bcol[8];
    #pragma unroll
    for (int n = 0; n < 8; ++n)
        bcol[n] = bias ? ldf(bias, boff + n * 16 + lr, f) : 0.f;

    float alA = statsA ? ldf(pa, bnl, f) : 0.f;
    const float invn = 1.f / (float)N_NODES;

    // ---- load A (fp32), BN+PReLU (head), emb write, convert to hi/mid/lo frags
    // lane holds A[row = arow][k = ks*32 + lg*8 + e], e=0..7
    bfrag ah[4], am[4], alo[4];
    const float4* A4 = (const float4*)A;
    #pragma unroll
    for (int ks = 0; ks < 4; ++ks) {
        int k0 = ks * 32 + lg * 8;
        float xv[8];
        if (rowok) {
            long bi = (long)arow * 32 + (k0 >> 2);
            float4 x0 = A4[bi], x1 = A4[bi + 1];
            xv[0] = x0.x; xv[1] = x0.y; xv[2] = x0.z; xv[3] = x0.w;
            xv[4] = x1.x; xv[5] = x1.y; xv[6] = x1.z; xv[7] = x1.w;
        } else {
            #pragma unroll
            for (int e = 0; e < 8; ++e) xv[e] = 0.f;
        }
        if (statsA) {
            #pragma unroll
            for (int e = 0; e < 8; ++e) {
                int c = k0 + e;
                float mean = statsA[c] * invn;
                float varv = statsA[128 + c] * invn - mean * mean;
                float s = ldf(gam, (long)bnl * DD + c, f) / sqrtf(varv + BN_EPS);
                float y = fmaf(xv[e], s, ldf(bet, (long)bnl * DD + c, f) - mean * s);
                xv[e] = (y > 0.f) ? y : alA * y;
            }
        }
        bfrag hfr, mfr, lfr;
        #pragma unroll
        for (int e = 0; e < 8; ++e) {
            unsigned short hb2 = f2bf(xv[e]);
            float r1 = xv[e] - bf2f(hb2);        // exact
            unsigned short mb2 = f2bf(r1);
            float r2 = r1 - bf2f(mb2);           // exact
            hfr[e] = (short)hb2;
            mfr[e] = (short)mb2;
            lfr[e] = (short)f2bf(r2);
        }
        ah[ks] = hfr; am[ks] = mfr; alo[ks] = lfr;
        if (embp && rowok) {                     // fused emb output (act(A))
            if (f) {
                ((float4*)embp)[(long)arow * 32 + (k0 >> 2)]     = make_float4(xv[0], xv[1], xv[2], xv[3]);
                ((float4*)embp)[(long)arow * 32 + (k0 >> 2) + 1] = make_float4(xv[4], xv[5], xv[6], xv[7]);
            } else {
                uint4 pk;
                pk.x = (unsigned)(unsigned short)hfr[0] | ((unsigned)(unsigned short)hfr[1] << 16);
                pk.y = (unsigned)(unsigned short)hfr[2] | ((unsigned)(unsigned short)hfr[3] << 16);
                pk.z = (unsigned)(unsigned short)hfr[4] | ((unsigned)(unsigned short)hfr[5] << 16);
                pk.w = (unsigned)(unsigned short)hfr[6] | ((unsigned)(unsigned short)hfr[7] << 16);
                ((uint4*)embp)[(long)arow * 16 + (k0 >> 3)] = pk;
            }
        }
    }

    float lsum[8], lsq[8];
    #pragma unroll
    for (int n2 = 0; n2 < 8; ++n2) { lsum[n2] = 0.f; lsq[n2] = 0.f; }

    // ---- two col-halves; per n-tile: complete K on dual accumulators, per-n epilogue
    #pragma unroll
    for (int h = 0; h < 2; ++h) {
        if (h) {
            __syncthreads();               // all waves done reading half 0
            #pragma unroll
            for (int u = 0; u < 12; ++u) {
                int chunk = w * 12 + u;
                gload_lds16(Wp + 24576 + chunk * 512 + lane * 8, &Wl[chunk * 512]);
            }
        }
        __syncthreads();                   // half staged (barrier drains vmcnt)

        #pragma unroll
        for (int nn = 0; nn < 4; ++nn) {
            int n = h * 4 + nn;
            bfrag bh[4], bm[4], bl[4];
            #pragma unroll
            for (int ks = 0; ks < 4; ++ks) {
                int bb = ((nn * 4 + ks) * 3) * 512 + lane * 8;
                bh[ks] = *(const bfrag*)&Wl[bb];
                bm[ks] = *(const bfrag*)&Wl[bb + 512];
                bl[ks] = *(const bfrag*)&Wl[bb + 1024];
            }
            f32x4 accA = (f32x4){0.f, 0.f, 0.f, 0.f};
            f32x4 accB = (f32x4){0.f, 0.f, 0.f, 0.f};
            #pragma unroll
            for (int ks = 0; ks < 4; ++ks) {
                accA = __builtin_amdgcn_mfma_f32_16x16x32_bf16(ah[ks],  bh[ks], accA, 0, 0, 0);
                accB = __builtin_amdgcn_mfma_f32_16x16x32_bf16(am[ks],  bh[ks], accB, 0, 0, 0);
                accA = __builtin_amdgcn_mfma_f32_16x16x32_bf16(ah[ks],  bm[ks], accA, 0, 0, 0);
                accB = __builtin_amdgcn_mfma_f32_16x16x32_bf16(am[ks],  bm[ks], accB, 0, 0, 0);
                accA = __builtin_amdgcn_mfma_f32_16x16x32_bf16(alo[ks], bh[ks], accA, 0, 0, 0);
                accB = __builtin_amdgcn_mfma_f32_16x16x32_bf16(ah[ks],  bl[ks], accB, 0, 0, 0);
            }
            // epilogue for col-tile n: D col = n*16+lr, row = rowbase + lg*4 + reg
            int colb = n * 16 + lr;
            #pragma unroll
            for (int reg = 0; reg < 4; ++reg) {
                int r2 = rowbase + lg * 4 + reg;
                if (r2 < N_NODES) {
                    float o = accA[reg] + accB[reg] + bcol[n];
                    if (relu) o = fmaxf(o, 0.f);
                    Cout[(long)r2 * 128 + colb] = o;
                    lsum[n] += o;
                    lsq[n] += o * o;
                }
            }
        }
    }

    if (stats) {
        #pragma unroll
        for (int n2 = 0; n2 < 8; ++n2) {
            lsum[n2] += __shfl_xor(lsum[n2], 16);
            lsum[n2] += __shfl_xor(lsum[n2], 32);
            lsq[n2]  += __shfl_xor(lsq[n2], 16);
            lsq[n2]  += __shfl_xor(lsq[n2], 32);
        }
        __syncthreads();                      // all Wl reads done -> safe to overlay
        float* red = (float*)Wl;              // [wave][256]
        if (lane < 16) {
            #pragma unroll
            for (int n2 = 0; n2 < 8; ++n2) {
                red[w * 256 + n2 * 16 + lane] = lsum[n2];
                red[w * 256 + 128 + n2 * 16 + lane] = lsq[n2];
            }
        }
        __syncthreads();
        float t = red[tid] + red[256 + tid] + red[512 + tid] + red[768 + tid];
        atomicAdd(&stats[tid], t);
    }
}

// ---- head: logits = hidden @ Wh2 + bh2 ; argmax (first-max tie-break) ----

__global__ __launch_bounds__(256) void k_head(const float* __restrict__ Hd, const void* __restrict__ W2,
                                              const void* __restrict__ b2,
                                              void* __restrict__ out_base,
                                              const int* __restrict__ dflag) {
    __shared__ float Wl[128][40];
    __shared__ float bl[40];
    __shared__ float rv[32][8];
    __shared__ int ri[32][8];
    int f = *dflag;
    int tid = threadIdx.x;
    for (int u = tid; u < 128 * 40; u += 256) Wl[u / 40][u % 40] = ldf(W2, u, f);
    if (tid < 40) bl[tid] = ldf(b2, tid, f);
    __syncthreads();
    int rl = tid >> 3, g = tid & 7;
    long r = (long)blockIdx.x * 32 + rl;            // 3125*32 == N exactly
    float acc[5];
    #pragma unroll
    for (int j = 0; j < 5; ++j) acc[j] = bl[g * 5 + j];
    for (int k = 0; k < 128; ++k) {
        float h = Hd[r * 128 + k];
        #pragma unroll
        for (int j = 0; j < 5; ++j) acc[j] += h * Wl[k][g * 5 + j];
    }
    float best = acc[0]; int bi = 0;
    #pragma unroll
    for (int j = 1; j < 5; ++j)
        if (acc[j] > best) { best = acc[j]; bi = j; }   // strictly > keeps first max
    const long LOG_OFF = (long)N_NODES * DD;
    const long ARG_OFF = (long)N_NODES * (DD + CC);
    #pragma unroll
    for (int j = 0; j < 5; ++j) stf(out_base, LOG_OFF + r * 40 + g * 5 + j, acc[j], f);
    rv[rl][g] = best; ri[rl][g] = g * 5 + bi;
    __syncthreads();
    if (tid < 32) {
        long row = (long)blockIdx.x * 32 + tid;
        float bb = rv[tid][0]; int bbi = ri[tid][0];
        #pragma unroll
        for (int g2 = 1; g2 < 8; ++g2)
            if (rv[tid][g2] > bb) { bb = rv[tid][g2]; bbi = ri[tid][g2]; }
        stf(out_base, ARG_OFF + row, (float)bbi, f);
    }
}

// ---------------- launch ----------------

extern "C" void kernel_launch(void* const* d_in, const int* in_sizes, int n_in,
                              void* d_out, int out_size, void* d_ws, size_t ws_size,
                              hipStream_t stream) {
    const void* x   = d_in[0];
    const int* ei   = (const int*)d_in[1];
    const void* Ws  = d_in[2];
    const void* bs  = d_in[3];
    const void* gam = d_in[4];
    const void* bet = d_in[5];
    const void* pa  = d_in[6];
    const void* Wh1 = d_in[7];
    const void* bh1 = d_in[8];
    const void* Wh2 = d_in[9];
    const void* bh2 = d_in[10];

    char* w = (char*)d_ws;
    int* cnt     = (int*)w;    w += sizeof(int) * N_NODES;
    int* fpos    = (int*)w;    w += sizeof(int) * N_NODES;
    int* rowptr  = (int*)w;    w += sizeof(int) * (N_NODES + 4);
    int2* adjw   = (int2*)w;   w += sizeof(int2) * N_EDGES;
    int* bsum    = (int*)w;    w += sizeof(int) * 512;
    int* dflag   = (int*)w;    w += sizeof(int) * 4;
    float* dinv  = (float*)w;  w += sizeof(float) * N_NODES;
    float* stats = (float*)w;  w += sizeof(float) * (6 * DD);
    unsigned short* Wp = (unsigned short*)w; w += sizeof(unsigned short) * 4 * 49152; // bf16 hi/mid/lo frags
    float* bufA  = (float*)w;  w += sizeof(float) * (size_t)N_NODES * DD;
    float* bufB  = (float*)w;  w += sizeof(float) * (size_t)N_NODES * DD;

    const int scanBlocks = (N_NODES + 255) / 256;       // 391
    const int edgeBlocks = (N_EDGES + 255) / 256;       // 2344
    const int gemmBlocks = (N_NODES + 63) / 64;         // 1563 row-tiles (64 rows/block)
    const int aggBlocks  = (N_NODES + 7) / 8;           // 12500 (8 rows/block, 1 per half-wave)

    k_detect<<<1, 256, 0, stream>>>(x, dflag);
    k_packw<<<256, 256, 0, stream>>>(Ws, Wh1, Wp, dflag);
    k_init<<<scanBlocks, 256, 0, stream>>>(cnt, fpos, rowptr, stats);
    k_count<<<edgeBlocks, 256, 0, stream>>>(ei, cnt);
    k_scan1<<<scanBlocks, 256, 0, stream>>>(cnt, rowptr, bsum, dinv);
    k_scan2<<<1, 512, 0, stream>>>(bsum, scanBlocks);
    k_scan3<<<scanBlocks, 256, 0, stream>>>(rowptr, bsum);
    k_fill<<<edgeBlocks, 256, 0, stream>>>(ei, fpos, rowptr, adjw, dinv);

    for (int l = 0; l < LL; ++l) {
        const void* src = (l == 0) ? x : (const void*)bufB;
        const float* st = (l == 0) ? nullptr : (stats + (l - 1) * 256);
        k_agg<<<aggBlocks, 256, 0, stream>>>(src, rowptr, adjw, dinv, st, gam, bet, pa,
                                             l - 1, bufA, dflag);
        k_gemm2<<<gemmBlocks, 256, 0, stream>>>(bufA, Wp + (size_t)l * 49152, bs, (long)l * DD,
                                                nullptr, gam, bet, pa, 0,
                                                stats + l * 256, bufB, nullptr, 0, dflag);
    }

    // head GEMM: BN_2+PReLU inline from stats, writes embeddings (fused k_emb) + hidden
    k_gemm2<<<gemmBlocks, 256, 0, stream>>>(bufB, Wp + (size_t)3 * 49152, bh1, 0,
                                            stats + 2 * 256, gam, bet, pa, 2,
                                            nullptr, bufA, d_out, 1, dflag);
    k_head<<<(N_NODES / 32), 256, 0, stream>>>(bufA, Wh2, bh2, d_out, dflag);
}

// Round 13
// 623.494 us; speedup vs baseline: 1.0724x; 1.0724x over previous
//
#include <hip/hip_runtime.h>
#include <hip/hip_bf16.h>
#include <cstddef>

#define N_NODES 100000
#define N_EDGES 600000
#define DD 128
#define LL 3
#define CC 40
#define BN_EPS 1e-5f

typedef __attribute__((ext_vector_type(8))) short bfrag;   // 8 bf16 = 4 VGPRs
typedef __attribute__((ext_vector_type(4))) float f32x4;

// dtype-adaptive load/store: f32!=0 -> buffer holds float32, else bfloat16.
__device__ __forceinline__ float ldf(const void* p, long i, int f32) {
    return f32 ? ((const float*)p)[i] : __bfloat162float(((const __hip_bfloat16*)p)[i]);
}
__device__ __forceinline__ void stf(void* p, long i, float v, int f32) {
    if (f32) ((float*)p)[i] = v;
    else     ((__hip_bfloat16*)p)[i] = __float2bfloat16(v);
}

// float -> bf16 bits with round-to-nearest-even (finite inputs)
__device__ __forceinline__ unsigned short f2bf(float f) {
    unsigned u = __float_as_uint(f);
    unsigned r = (u + 0x7fffu + ((u >> 16) & 1u)) >> 16;
    return (unsigned short)r;
}
__device__ __forceinline__ float bf2f(unsigned short h) {
    return __uint_as_float(((unsigned)h) << 16);
}

// async global->LDS, 16B per lane (dest = wave-uniform base + lane*16)
__device__ __forceinline__ void gload_lds16(const unsigned short* g, unsigned short* l) {
    __builtin_amdgcn_global_load_lds((const __attribute__((address_space(1))) unsigned int*)g,
                                     (__attribute__((address_space(3))) unsigned int*)l, 16, 0, 0);
}

// ---------------- dtype detection (fp32 data read as bf16 -> garbage values) ----------------
__global__ __launch_bounds__(256) void k_detect(const void* __restrict__ x, int* __restrict__ dflag) {
    __shared__ int s[256];
    int t = threadIdx.x;
    const __hip_bfloat16* xb = (const __hip_bfloat16*)x;
    int bad = 0;
    for (int i = t; i < 4096; i += 256) {
        float v = __bfloat162float(xb[i]);
        float a = fabsf(v);
        if (!(a < 1e6f)) bad++;
        else if (v != 0.f && a < 1e-30f) bad++;
    }
    s[t] = bad; __syncthreads();
    for (int off = 128; off > 0; off >>= 1) {
        if (t < off) s[t] += s[t + off];
        __syncthreads();
    }
    if (t == 0) *dflag = (s[0] > 64) ? 1 : 0;
}

// ---------------- weight packing: fp32 W[128x128] -> bf16 hi/mid/lo planes, MFMA fragment order ----
// B-frag layout (16x16x32): lane holds W[k = ks*32 + (lane>>4)*8 + j][n*16 + (lane&15)].
// Packed (bf16 units, per matrix 49152): frag (n,ks,plane) at ((n*4+ks)*3+plane)*512 + lane*8 + j.
// n-major => one 64-col half (n 0..3 or 4..7) is a contiguous 24576-short (48 KB) range.
__global__ __launch_bounds__(256) void k_packw(const void* __restrict__ Ws, const void* __restrict__ Wh1,
                                               unsigned short* __restrict__ Wp,
                                               const int* __restrict__ dflag) {
    int f = *dflag;
    int u = blockIdx.x * 256 + threadIdx.x;      // 0 .. 65535 (4 matrices x 16384)
    int mat = u >> 14;
    int r = u & 16383;
    int k = r >> 7, c = r & 127;
    float wv = (mat < 3) ? ldf(Ws, (long)mat * 16384 + r, f) : ldf(Wh1, r, f);
    unsigned short hi = f2bf(wv);
    float r1 = wv - bf2f(hi);        // exact
    unsigned short mid = f2bf(r1);
    float r2 = r1 - bf2f(mid);       // exact
    unsigned short lo = f2bf(r2);
    int n = c >> 4, ks = k >> 5, j = k & 7;
    int lanep = (c & 15) | (((k >> 3) & 3) << 4);
    long base = (long)mat * 49152 + (long)((n * 4 + ks) * 3) * 512 + lanep * 8 + j;
    Wp[base] = hi;
    Wp[base + 512] = mid;
    Wp[base + 1024] = lo;
}

// ---------------- graph preprocessing ----------------

__global__ __launch_bounds__(256) void k_init(int* cnt, int* fpos, int* rowptr, float* stats) {
    int i = blockIdx.x * 256 + threadIdx.x;
    if (i < N_NODES) { cnt[i] = 0; fpos[i] = 0; }
    if (i < 6 * DD) stats[i] = 0.f;       // 3 layers x (sum[128], sumsq[128])
    if (i == 0) rowptr[N_NODES] = N_EDGES;
}

__global__ __launch_bounds__(256) void k_count(const int* __restrict__ ei, int* __restrict__ cnt) {
    int e = blockIdx.x * 256 + threadIdx.x;
    if (e < N_EDGES) atomicAdd(&cnt[ei[N_EDGES + e]], 1);  // dst row
}

__global__ __launch_bounds__(256) void k_scan1(const int* __restrict__ cnt, int* __restrict__ rowptr,
                                               int* __restrict__ bsum, float* __restrict__ dinv) {
    __shared__ int s[256];
    int t = threadIdx.x;
    int i = blockIdx.x * 256 + t;
    int v = (i < N_NODES) ? cnt[i] : 0;
    if (i < N_NODES) dinv[i] = 1.f / sqrtf((float)(1 + v));  // deg >= 1 (self-loop)
    s[t] = v; __syncthreads();
    for (int off = 1; off < 256; off <<= 1) {
        int x = (t >= off) ? s[t - off] : 0;
        __syncthreads();
        s[t] += x; __syncthreads();
    }
    if (i < N_NODES) rowptr[i] = s[t] - v;
    if (t == 255) bsum[blockIdx.x] = s[255];
}

__global__ __launch_bounds__(512) void k_scan2(int* bsum, int nb) {
    __shared__ int s[512];
    int t = threadIdx.x;
    int v = (t < nb) ? bsum[t] : 0;
    s[t] = v; __syncthreads();
    for (int off = 1; off < 512; off <<= 1) {
        int x = (t >= off) ? s[t - off] : 0;
        __syncthreads();
        s[t] += x; __syncthreads();
    }
    if (t < nb) bsum[t] = s[t] - v;
}

__global__ __launch_bounds__(256) void k_scan3(int* rowptr, const int* __restrict__ bsum) {
    int i = blockIdx.x * 256 + threadIdx.x;
    if (i < N_NODES) rowptr[i] += bsum[blockIdx.x];
}

// fill CSR adjacency as (src, dinv[src]) pairs: one coalesced int2 stream for k_agg
__global__ __launch_bounds__(256) void k_fill(const int* __restrict__ ei, int* __restrict__ fpos,
                                              const int* __restrict__ rowptr, int2* __restrict__ adjw,
                                              const float* __restrict__ dinv) {
    int e = blockIdx.x * 256 + threadIdx.x;
    if (e < N_EDGES) {
        int s = ei[e];
        int d = ei[N_EDGES + e];
        int p = atomicAdd(&fpos[d], 1);
        adjw[rowptr[d] + p] = make_int2(s, __float_as_int(dinv[s]));
    }
}

// ---- gather one feature row as float4 per 32-lane half: lane q owns elems 4q..4q+3 ----
__device__ __forceinline__ float4 load_row4(const void* __restrict__ src, long row, int q, int f) {
    if (f) {
        return ((const float4*)src)[row * 32 + q];
    } else {
        uint2 u = ((const uint2*)src)[row * 32 + q];
        float4 v;
        v.x = __uint_as_float(u.x << 16);
        v.y = __uint_as_float(u.x & 0xffff0000u);
        v.z = __uint_as_float(u.y << 16);
        v.w = __uint_as_float(u.y & 0xffff0000u);
        return v;
    }
}

__device__ __forceinline__ float4 bn4(float4 v, float4 sc, float4 sh, float al) {
    float y;
    y = fmaf(v.x, sc.x, sh.x); v.x = (y > 0.f) ? y : al * y;
    y = fmaf(v.y, sc.y, sh.y); v.y = (y > 0.f) ? y : al * y;
    y = fmaf(v.z, sc.z, sh.z); v.z = (y > 0.f) ? y : al * y;
    y = fmaf(v.w, sc.w, sh.w); v.w = (y > 0.f) ? y : al * y;
    return v;
}

// ---- CSR aggregation (agg-first): out_i = dinv_i*(dinv_i*act_i + sum_j dinv_j*act_j) ----
// act = identity for layer 0 (stats==null), else BN_{bnl}+PReLU with per-channel scale/shift
// computed ONCE PER BLOCK into LDS (threads 0-127), not per row.
// One wave per row; the two 32-lane halves gather DIFFERENT edges (2 in flight per half,
// step-4 loop = minimal padding for Poisson(6) degrees). adjw = (src, dinv[src]) pairs.
// Measured floor ~66 us across 3 MLP structures; traffic reduction is precision-blocked.

__global__ __launch_bounds__(256) void k_agg(const void* __restrict__ src,
                                             const int* __restrict__ rowptr,
                                             const int2* __restrict__ adjw,
                                             const float* __restrict__ dinv,
                                             const float* __restrict__ stats,
                                             const void* __restrict__ gam,
                                             const void* __restrict__ bet,
                                             const void* __restrict__ pa,
                                             int bnl,
                                             float* __restrict__ outp,
                                             const int* __restrict__ dflag) {
    __shared__ float s_bn[260];            // sc[128], sh[128], alpha
    int f = *dflag;
    int tid = threadIdx.x;
    bool useBN = (stats != nullptr);
    if (useBN) {                           // per-block BN prep (uniform branch)
        if (tid < 128) {
            const float invn = 1.f / (float)N_NODES;
            float mean = stats[tid] * invn;
            float varv = stats[128 + tid] * invn - mean * mean;
            float s = ldf(gam, (long)bnl * DD + tid, f) / sqrtf(varv + BN_EPS);
            s_bn[tid] = s;
            s_bn[128 + tid] = ldf(bet, (long)bnl * DD + tid, f) - mean * s;
        }
        if (tid == 0) s_bn[256] = ldf(pa, bnl, f);
        __syncthreads();
    }

    int lane = tid & 63;
    int h = lane >> 5;                 // half: 0 or 1
    int q = lane & 31;                 // owns elems 4q..4q+3
    int i = blockIdx.x * 4 + (tid >> 6);
    if (i >= N_NODES) return;

    float4 sc = make_float4(1.f, 1.f, 1.f, 1.f);
    float4 sh = make_float4(0.f, 0.f, 0.f, 0.f);
    float al = 0.f;
    if (useBN) {
        sc = ((const float4*)s_bn)[q];
        sh = ((const float4*)(s_bn + 128))[q];
        al = s_bn[256];
    }

    float di = dinv[i];
    int e0 = rowptr[i], e1 = rowptr[i + 1];

    float a0 = 0.f, a1 = 0.f, a2 = 0.f, a3 = 0.f;
    if (h == 0) {                      // self term on half 0
        float4 v = load_row4(src, i, q, f);
        if (useBN) v = bn4(v, sc, sh, al);
        a0 = di * v.x; a1 = di * v.y; a2 = di * v.z; a3 = di * v.w;
    }

    for (int base = e0; base < e1; base += 64) {
        int m = e1 - base; if (m > 64) m = 64;
        int2 aw = (lane < m) ? adjw[base + lane] : make_int2(0, 0);   // coalesced 8B
        int ajl = aw.x;
        float wl = __int_as_float(aw.y);                               // zero beyond m
        for (int t = 0; t < m; t += 4) {
            int s0 = t + h;     if (s0 > 63) s0 = 63;                  // wl beyond m is 0
            int s1 = t + 2 + h; if (s1 > 63) s1 = 63;
            int j0 = __shfl(ajl, s0), j1 = __shfl(ajl, s1);
            float w0 = __shfl(wl, s0), w1 = __shfl(wl, s1);
            float4 v0 = load_row4(src, j0, q, f);                      // 2 gathers in flight
            float4 v1 = load_row4(src, j1, q, f);
            if (useBN) {
                v0 = bn4(v0, sc, sh, al);
                v1 = bn4(v1, sc, sh, al);
            }
            a0 += w0 * v0.x + w1 * v1.x;
            a1 += w0 * v0.y + w1 * v1.y;
            a2 += w0 * v0.z + w1 * v1.z;
            a3 += w0 * v0.w + w1 * v1.w;
        }
    }

    // merge halves (both halves hold elems 4q..4q+3)
    a0 += __shfl_xor(a0, 32);
    a1 += __shfl_xor(a1, 32);
    a2 += __shfl_xor(a2, 32);
    a3 += __shfl_xor(a3, 32);

    if (h == 0) {
        float4 r = make_float4(di * a0, di * a1, di * a2, di * a3);
        ((float4*)outp)[(size_t)i * 32 + q] = r;
    }
}

// ---- MFMA GEMM: C[N x 128] = act(A)[N x 128] * W[128 x 128] + bias (opt relu) ----
// W pre-packed bf16 hi/mid/lo planes (k_packw); A split 3-way in-register.
// 6-term product (hh, hm, mh, mm, hl, lh), fp32 accumulate.
// Two 64-col halves (48 KB LDS each); half-0 stage issued async (global_load_lds) BEFORE
// the A-load/convert so its latency hides under the convert VALU.
// 128 rows/block, 32 rows/wave. NOTE: the 64-row variant (R7/R12) is faster per-kernel
// (76 vs 91 us) but inflates TOTAL by ~45 us both times tried — do not transplant.
// statsA: BN_{bnl}+PReLU on A inline from stats (head GEMM); embp: write act(A) (= embeddings).
// stats: atomicAdd per-col sum/sumsq of C.

__global__ __launch_bounds__(256, 2) void k_gemm2(const float* __restrict__ A,
                                                  const unsigned short* __restrict__ Wp,
                                                  const void* __restrict__ bias, long boff,
                                                  const float* __restrict__ statsA,
                                                  const void* __restrict__ gam,
                                                  const void* __restrict__ bet,
                                                  const void* __restrict__ pa, int bnl,
                                                  float* __restrict__ stats,
                                                  float* __restrict__ Cout,
                                                  void* __restrict__ embp, int relu,
                                                  const int* __restrict__ dflag) {
    __shared__ unsigned short Wl[24576];          // 48 KB: one 64-col half (hi/mid/lo frags)
    int f = *dflag;
    int tid = threadIdx.x;
    int lane = tid & 63;
    int w = tid >> 6;

    // ---- stage half 0 async (12 x 1KB chunks per wave, linear identity copy)
    #pragma unroll
    for (int u = 0; u < 12; ++u) {
        int chunk = w * 12 + u;
        gload_lds16(Wp + chunk * 512 + lane * 8, &Wl[chunk * 512]);
    }

    int lr = lane & 15;               // A-row-in-subtile / C-col-in-tile
    int lg = lane >> 4;               // 0..3 (k-group)
    int rowbase = blockIdx.x * 128 + w * 32;

    float bcol[8];
    #pragma unroll
    for (int n = 0; n < 8; ++n)
        bcol[n] = bias ? ldf(bias, boff + n * 16 + lr, f) : 0.f;

    float alA = statsA ? ldf(pa, bnl, f) : 0.f;
    const float invn = 1.f / (float)N_NODES;

    // ---- load A fragments (fp32 -> bf16 hi/mid/lo):
    // lane holds A[row = base + s*16 + (lane&15)][k = ks*32 + lg*8 + e], e=0..7
    bfrag ah[2][4], am[2][4], alo[2][4];
    const float4* A4 = (const float4*)A;
    #pragma unroll
    for (int ks = 0; ks < 4; ++ks) {
        int k0 = ks * 32 + lg * 8;
        float bs_[8], bh_[8];
        if (statsA) {
            #pragma unroll
            for (int e = 0; e < 8; ++e) {
                int c = k0 + e;
                float mean = statsA[c] * invn;
                float varv = statsA[128 + c] * invn - mean * mean;
                float s = ldf(gam, (long)bnl * DD + c, f) / sqrtf(varv + BN_EPS);
                bs_[e] = s;
                bh_[e] = ldf(bet, (long)bnl * DD + c, f) - mean * s;
            }
        }
        #pragma unroll
        for (int s = 0; s < 2; ++s) {
            int row = rowbase + s * 16 + lr;
            float xv[8];
            if (row < N_NODES) {
                long bi = (long)row * 32 + (k0 >> 2);
                float4 x0 = A4[bi], x1 = A4[bi + 1];
                xv[0] = x0.x; xv[1] = x0.y; xv[2] = x0.z; xv[3] = x0.w;
                xv[4] = x1.x; xv[5] = x1.y; xv[6] = x1.z; xv[7] = x1.w;
            } else {
                #pragma unroll
                for (int e = 0; e < 8; ++e) xv[e] = 0.f;
            }
            if (statsA) {
                #pragma unroll
                for (int e = 0; e < 8; ++e) {
                    float y = fmaf(xv[e], bs_[e], bh_[e]);
                    xv[e] = (y > 0.f) ? y : alA * y;
                }
            }
            bfrag hfr, mfr, lfr;
            #pragma unroll
            for (int e = 0; e < 8; ++e) {
                unsigned short hb2 = f2bf(xv[e]);
                float r1 = xv[e] - bf2f(hb2);        // exact
                unsigned short mb2 = f2bf(r1);
                float r2 = r1 - bf2f(mb2);           // exact
                hfr[e] = (short)hb2;
                mfr[e] = (short)mb2;
                lfr[e] = (short)f2bf(r2);
            }
            ah[s][ks] = hfr;
            am[s][ks] = mfr;
            alo[s][ks] = lfr;
            if (embp && row < N_NODES) {             // fused emb output (act(A))
                if (f) {
                    ((float4*)embp)[(long)row * 32 + (k0 >> 2)]     = make_float4(xv[0], xv[1], xv[2], xv[3]);
                    ((float4*)embp)[(long)row * 32 + (k0 >> 2) + 1] = make_float4(xv[4], xv[5], xv[6], xv[7]);
                } else {
                    uint4 pk;
                    pk.x = (unsigned)(unsigned short)hfr[0] | ((unsigned)(unsigned short)hfr[1] << 16);
                    pk.y = (unsigned)(unsigned short)hfr[2] | ((unsigned)(unsigned short)hfr[3] << 16);
                    pk.z = (unsigned)(unsigned short)hfr[4] | ((unsigned)(unsigned short)hfr[5] << 16);
                    pk.w = (unsigned)(unsigned short)hfr[6] | ((unsigned)(unsigned short)hfr[7] << 16);
                    ((uint4*)embp)[(long)row * 16 + (k0 >> 3)] = pk;
                }
            }
        }
    }

    f32x4 acc[2][8];
    #pragma unroll
    for (int s = 0; s < 2; ++s)
        #pragma unroll
        for (int n = 0; n < 8; ++n) acc[s][n] = (f32x4){0.f, 0.f, 0.f, 0.f};

    __syncthreads();                   // half-0 staged (barrier drains vmcnt)

    #pragma unroll
    for (int nn = 0; nn < 4; ++nn) {
        int n = nn;
        bfrag bh[4], bm[4], bl[4];
        #pragma unroll
        for (int ks = 0; ks < 4; ++ks) {
            int base = ((nn * 4 + ks) * 3) * 512 + lane * 8;
            bh[ks] = *(const bfrag*)&Wl[base];
            bm[ks] = *(const bfrag*)&Wl[base + 512];
            bl[ks] = *(const bfrag*)&Wl[base + 1024];
        }
        #pragma unroll
        for (int ks = 0; ks < 4; ++ks) {
            #pragma unroll
            for (int s = 0; s < 2; ++s) {
                acc[s][n] = __builtin_amdgcn_mfma_f32_16x16x32_bf16(ah[s][ks],  bh[ks], acc[s][n], 0, 0, 0);
                acc[s][n] = __builtin_amdgcn_mfma_f32_16x16x32_bf16(am[s][ks],  bh[ks], acc[s][n], 0, 0, 0);
                acc[s][n] = __builtin_amdgcn_mfma_f32_16x16x32_bf16(ah[s][ks],  bm[ks], acc[s][n], 0, 0, 0);
                acc[s][n] = __builtin_amdgcn_mfma_f32_16x16x32_bf16(am[s][ks],  bm[ks], acc[s][n], 0, 0, 0);
                acc[s][n] = __builtin_amdgcn_mfma_f32_16x16x32_bf16(alo[s][ks], bh[ks], acc[s][n], 0, 0, 0);
                acc[s][n] = __builtin_amdgcn_mfma_f32_16x16x32_bf16(ah[s][ks],  bl[ks], acc[s][n], 0, 0, 0);
            }
        }
    }

    __syncthreads();                   // all waves done reading half 0
    #pragma unroll
    for (int u = 0; u < 12; ++u) {
        int chunk = w * 12 + u;
        gload_lds16(Wp + 24576 + chunk * 512 + lane * 8, &Wl[chunk * 512]);
    }
    __syncthreads();                   // half-1 staged

    #pragma unroll
    for (int nn = 0; nn < 4; ++nn) {
        int n = 4 + nn;
        bfrag bh[4], bm[4], bl[4];
        #pragma unroll
        for (int ks = 0; ks < 4; ++ks) {
            int base = ((nn * 4 + ks) * 3) * 512 + lane * 8;
            bh[ks] = *(const bfrag*)&Wl[base];
            bm[ks] = *(const bfrag*)&Wl[base + 512];
            bl[ks] = *(const bfrag*)&Wl[base + 1024];
        }
        #pragma unroll
        for (int ks = 0; ks < 4; ++ks) {
            #pragma unroll
            for (int s = 0; s < 2; ++s) {
                acc[s][n] = __builtin_amdgcn_mfma_f32_16x16x32_bf16(ah[s][ks],  bh[ks], acc[s][n], 0, 0, 0);
                acc[s][n] = __builtin_amdgcn_mfma_f32_16x16x32_bf16(am[s][ks],  bh[ks], acc[s][n], 0, 0, 0);
                acc[s][n] = __builtin_amdgcn_mfma_f32_16x16x32_bf16(ah[s][ks],  bm[ks], acc[s][n], 0, 0, 0);
                acc[s][n] = __builtin_amdgcn_mfma_f32_16x16x32_bf16(am[s][ks],  bm[ks], acc[s][n], 0, 0, 0);
                acc[s][n] = __builtin_amdgcn_mfma_f32_16x16x32_bf16(alo[s][ks], bh[ks], acc[s][n], 0, 0, 0);
                acc[s][n] = __builtin_amdgcn_mfma_f32_16x16x32_bf16(ah[s][ks],  bl[ks], acc[s][n], 0, 0, 0);
            }
        }
    }

    // ---- epilogue: bias (+relu), store, per-col stats
    // D layout: col = n*16 + (lane&15); row = base + s*16 + lg*4 + reg
    int rowst[2][4]; bool rv[2][4];
    #pragma unroll
    for (int s = 0; s < 2; ++s)
        #pragma unroll
        for (int reg = 0; reg < 4; ++reg) {
            rowst[s][reg] = rowbase + s * 16 + lg * 4 + reg;
            rv[s][reg] = rowst[s][reg] < N_NODES;
        }

    float ls[8], lq[8];
    #pragma unroll
    for (int n = 0; n < 8; ++n) { ls[n] = 0.f; lq[n] = 0.f; }

    #pragma unroll
    for (int s = 0; s < 2; ++s)
        #pragma unroll
        for (int n = 0; n < 8; ++n) {
            int colb = n * 16 + lr;
            #pragma unroll
            for (int reg = 0; reg < 4; ++reg) {
                if (rv[s][reg]) {
                    float o = acc[s][n][reg] + bcol[n];
                    if (relu) o = fmaxf(o, 0.f);
                    Cout[(long)rowst[s][reg] * 128 + colb] = o;
                    ls[n] += o;
                    lq[n] += o * o;
                }
            }
        }

    if (stats) {
        #pragma unroll
        for (int n = 0; n < 8; ++n) {
            ls[n] += __shfl_xor(ls[n], 16);
            ls[n] += __shfl_xor(ls[n], 32);
            lq[n] += __shfl_xor(lq[n], 16);
            lq[n] += __shfl_xor(lq[n], 32);
        }
        __syncthreads();                      // all waves done reading Wl
        float* red = (float*)Wl;              // reuse LDS: [wave][256]
        if (lane < 16) {
            #pragma unroll
            for (int n = 0; n < 8; ++n) {
                red[w * 256 + n * 16 + lane] = ls[n];
                red[w * 256 + 128 + n * 16 + lane] = lq[n];
            }
        }
        __syncthreads();
        float t = red[tid] + red[256 + tid] + red[512 + tid] + red[768 + tid];
        atomicAdd(&stats[tid], t);
    }
}

// ---- head: logits = hidden @ Wh2 + bh2 ; argmax (first-max tie-break) ----

__global__ __launch_bounds__(256) void k_head(const float* __restrict__ Hd, const void* __restrict__ W2,
                                              const void* __restrict__ b2,
                                              void* __restrict__ out_base,
                                              const int* __restrict__ dflag) {
    __shared__ float Wl[128][40];
    __shared__ float bl[40];
    __shared__ float rv[32][8];
    __shared__ int ri[32][8];
    int f = *dflag;
    int tid = threadIdx.x;
    for (int u = tid; u < 128 * 40; u += 256) Wl[u / 40][u % 40] = ldf(W2, u, f);
    if (tid < 40) bl[tid] = ldf(b2, tid, f);
    __syncthreads();
    int rl = tid >> 3, g = tid & 7;
    long r = (long)blockIdx.x * 32 + rl;            // 3125*32 == N exactly
    float acc[5];
    #pragma unroll
    for (int j = 0; j < 5; ++j) acc[j] = bl[g * 5 + j];
    for (int k = 0; k < 128; ++k) {
        float h = Hd[r * 128 + k];
        #pragma unroll
        for (int j = 0; j < 5; ++j) acc[j] += h * Wl[k][g * 5 + j];
    }
    float best = acc[0]; int bi = 0;
    #pragma unroll
    for (int j = 1; j < 5; ++j)
        if (acc[j] > best) { best = acc[j]; bi = j; }   // strictly > keeps first max
    const long LOG_OFF = (long)N_NODES * DD;
    const long ARG_OFF = (long)N_NODES * (DD + CC);
    #pragma unroll
    for (int j = 0; j < 5; ++j) stf(out_base, LOG_OFF + r * 40 + g * 5 + j, acc[j], f);
    rv[rl][g] = best; ri[rl][g] = g * 5 + bi;
    __syncthreads();
    if (tid < 32) {
        long row = (long)blockIdx.x * 32 + tid;
        float bb = rv[tid][0]; int bbi = ri[tid][0];
        #pragma unroll
        for (int g2 = 1; g2 < 8; ++g2)
            if (rv[tid][g2] > bb) { bb = rv[tid][g2]; bbi = ri[tid][g2]; }
        stf(out_base, ARG_OFF + row, (float)bbi, f);
    }
}

// ---------------- launch ----------------

extern "C" void kernel_launch(void* const* d_in, const int* in_sizes, int n_in,
                              void* d_out, int out_size, void* d_ws, size_t ws_size,
                              hipStream_t stream) {
    const void* x   = d_in[0];
    const int* ei   = (const int*)d_in[1];
    const void* Ws  = d_in[2];
    const void* bs  = d_in[3];
    const void* gam = d_in[4];
    const void* bet = d_in[5];
    const void* pa  = d_in[6];
    const void* Wh1 = d_in[7];
    const void* bh1 = d_in[8];
    const void* Wh2 = d_in[9];
    const void* bh2 = d_in[10];

    char* w = (char*)d_ws;
    int* cnt     = (int*)w;    w += sizeof(int) * N_NODES;
    int* fpos    = (int*)w;    w += sizeof(int) * N_NODES;
    int* rowptr  = (int*)w;    w += sizeof(int) * (N_NODES + 4);
    int2* adjw   = (int2*)w;   w += sizeof(int2) * N_EDGES;
    int* bsum    = (int*)w;    w += sizeof(int) * 512;
    int* dflag   = (int*)w;    w += sizeof(int) * 4;
    float* dinv  = (float*)w;  w += sizeof(float) * N_NODES;
    float* stats = (float*)w;  w += sizeof(float) * (6 * DD);
    unsigned short* Wp = (unsigned short*)w; w += sizeof(unsigned short) * 4 * 49152; // bf16 hi/mid/lo frags
    float* bufA  = (float*)w;  w += sizeof(float) * (size_t)N_NODES * DD;
    float* bufB  = (float*)w;  w += sizeof(float) * (size_t)N_NODES * DD;

    const int scanBlocks = (N_NODES + 255) / 256;       // 391
    const int edgeBlocks = (N_EDGES + 255) / 256;       // 2344
    const int gemmBlocks = (N_NODES + 127) / 128;       // 782 row-tiles
    const int aggBlocks  = (N_NODES + 3) / 4;           // 25000

    k_detect<<<1, 256, 0, stream>>>(x, dflag);
    k_packw<<<256, 256, 0, stream>>>(Ws, Wh1, Wp, dflag);
    k_init<<<scanBlocks, 256, 0, stream>>>(cnt, fpos, rowptr, stats);
    k_count<<<edgeBlocks, 256, 0, stream>>>(ei, cnt);
    k_scan1<<<scanBlocks, 256, 0, stream>>>(cnt, rowptr, bsum, dinv);
    k_scan2<<<1, 512, 0, stream>>>(bsum, scanBlocks);
    k_scan3<<<scanBlocks, 256, 0, stream>>>(rowptr, bsum);
    k_fill<<<edgeBlocks, 256, 0, stream>>>(ei, fpos, rowptr, adjw, dinv);

    for (int l = 0; l < LL; ++l) {
        const void* src = (l == 0) ? x : (const void*)bufB;
        const float* st = (l == 0) ? nullptr : (stats + (l - 1) * 256);
        k_agg<<<aggBlocks, 256, 0, stream>>>(src, rowptr, adjw, dinv, st, gam, bet, pa,
                                             l - 1, bufA, dflag);
        k_gemm2<<<gemmBlocks, 256, 0, stream>>>(bufA, Wp + (size_t)l * 49152, bs, (long)l * DD,
                                                nullptr, gam, bet, pa, 0,
                                                stats + l * 256, bufB, nullptr, 0, dflag);
    }

    // head GEMM: BN_2+PReLU inline from stats, writes embeddings (fused k_emb) + hidden
    k_gemm2<<<gemmBlocks, 256, 0, stream>>>(bufB, Wp + (size_t)3 * 49152, bh1, 0,
                                            stats + 2 * 256, gam, bet, pa, 2,
                                            nullptr, bufA, d_out, 1, dflag);
    k_head<<<(N_NODES / 32), 256, 0, stream>>>(bufA, Wh2, bh2, d_out, dflag);
}